// Round 6
// baseline (193.511 us; speedup 1.0000x reference)
//
#include <hip/hip_runtime.h>
#include <math.h>

#define BATCH 256
#define NPTS  20000

// =====================================================================
// R6: ONE fused kernel = R4's gram (bit-identical partial grouping,
// 16 virtual waves = 4 chunks x 4 waves, exact double-sum association)
// + R4's PASSING readlane-based ssyevd path, verbatim.
// Only delta vs R4: fusion (no partial-buffer round trip, one dispatch).
// =====================================================================

__device__ __forceinline__ float f_sign(float a, float b) {
    return (b >= 0.0f) ? fabsf(a) : -fabsf(a);
}

__device__ __forceinline__ float slapy2(float xx, float yy) {
    float xa = fabsf(xx), ya = fabsf(yy);
    float w_ = fmaxf(xa, ya), z_ = fminf(xa, ya);
    if (z_ == 0.0f) return w_;
    float t = z_ / w_;
    return w_ * sqrtf(1.0f + t * t);
}

// lane-broadcast read of a lane-distributed register value (uniform idx)
__device__ __forceinline__ float rdl(float v, int i) {
    return __int_as_float(__builtin_amdgcn_readlane(__float_as_int(v), i));
}

// LAPACK 3.10+ slartg; ssteqr passes (G, F) -- G first.
__device__ __forceinline__ void slartg(float f, float g, float* cs, float* sn, float* r) {
    if (g == 0.0f) { *cs = 1.0f; *sn = 0.0f; *r = f; }
    else if (f == 0.0f) { *cs = 0.0f; *sn = (g >= 0.0f) ? 1.0f : -1.0f; *r = fabsf(g); }
    else {
        float dd2 = sqrtf(f * f + g * g);
        *cs = fabsf(f) / dd2;
        *r  = f_sign(dd2, f);
        *sn = g / (*r);
    }
}

__device__ void slaev2(float a, float b, float c_, float* rt1, float* rt2,
                       float* cs1, float* sn1) {
    float sm = a + c_;
    float df = a - c_;
    float adf = fabsf(df);
    float tb = b + b;
    float ab = fabsf(tb);
    float acmx, acmn;
    if (fabsf(a) > fabsf(c_)) { acmx = a; acmn = c_; } else { acmx = c_; acmn = a; }
    float rt;
    if (adf > ab)      { float t = ab / adf; rt = adf * sqrtf(1.0f + t * t); }
    else if (adf < ab) { float t = adf / ab; rt = ab * sqrtf(1.0f + t * t); }
    else               { rt = ab * sqrtf(2.0f); }
    int sgn1;
    if (sm < 0.0f) {
        *rt1 = 0.5f * (sm - rt); sgn1 = -1;
        *rt2 = (acmx / (*rt1)) * acmn - (b / (*rt1)) * b;
    } else if (sm > 0.0f) {
        *rt1 = 0.5f * (sm + rt); sgn1 = 1;
        *rt2 = (acmx / (*rt1)) * acmn - (b / (*rt1)) * b;
    } else {
        *rt1 = 0.5f * rt; *rt2 = -0.5f * rt; sgn1 = 1;
    }
    float cs; int sgn2;
    if (df >= 0.0f) { cs = df + rt; sgn2 = 1; } else { cs = df - rt; sgn2 = -1; }
    float acs = fabsf(cs);
    if (acs > ab) {
        float ct = -tb / cs;
        *sn1 = 1.0f / sqrtf(1.0f + ct * ct);
        *cs1 = ct * (*sn1);
    } else {
        if (ab == 0.0f) { *cs1 = 1.0f; *sn1 = 0.0f; }
        else {
            float tn = -cs / tb;
            *cs1 = 1.0f / sqrtf(1.0f + tn * tn);
            *sn1 = tn * (*cs1);
        }
    }
    if (sgn1 == sgn2) { float tn = *cs1; *cs1 = -(*sn1); *sn1 = tn; }
}

// identity-padded sweep applies (exact no-ops where c=1,s=0)
#define APPLY_QL() do { \
    _Pragma("unroll") \
    for (int jz = 8; jz >= 1; --jz) { \
        float cj = rdl(r_cw, jz), sj = rdl(r_sw, jz); \
        float tmpz = zz[jz + 1]; \
        zz[jz + 1] = cj * tmpz - sj * zz[jz]; \
        zz[jz]     = sj * tmpz + cj * zz[jz]; \
    } } while (0)

#define APPLY_QR() do { \
    _Pragma("unroll") \
    for (int jz = 1; jz <= 8; ++jz) { \
        float cj = rdl(r_cw, jz), sj = rdl(r_sw, jz); \
        float tmpz = zz[jz + 1]; \
        zz[jz + 1] = cj * tmpz - sj * zz[jz]; \
        zz[jz]     = sj * tmpz + cj * zz[jz]; \
    } } while (0)

__global__ __launch_bounds__(512) void fused_kernel(
    const float4* __restrict__ x, const float* __restrict__ wgt,
    float* __restrict__ out)
{
    const int n = 9;
    int b = blockIdx.x;
    int tid = threadIdx.x;
    int lane = tid & 63;
    int rw = tid >> 6;             // real wave 0..7

    __shared__ float red[16][45];  // 16 virtual waves (4 chunks x 4)
    __shared__ float A[10][10];
    __shared__ float Zl[10][10];
    __shared__ float ddl[11], eel[11], tau[10], wvl[10], zvl[10];

    // ========== gram phase: replicate R4's exact partial grouping ==========
    // R4: grid(b,chunk) x 256 threads; thread tid=wvc*64+lane covers points
    // chunk*5000 + wvc*64 + lane + 256*t. Virtual wave v = chunk*4 + wvc.
    // Real wave rw runs v = 2*rw and 2*rw+1 (independent float accumulations).
    for (int half = 0; half < 2; ++half) {
        int v = rw * 2 + half;
        int chunk = v >> 2, wvc = v & 3;
        float acc[45];
#pragma unroll
        for (int k = 0; k < 45; ++k) acc[k] = 0.0f;

        const float4* xb = x + (size_t)b * NPTS;
        const float*  wb = wgt + (size_t)b * NPTS;
        int base = chunk * 5000;
        for (int nn = base + wvc * 64 + lane; nn < base + 5000; nn += 256) {
            float4 vv = xb[nn];
            float wt = wb[nn];
            float X[9];
            X[0] = vv.z * vv.x; X[1] = vv.z * vv.y; X[2] = vv.z;
            X[3] = vv.w * vv.x; X[4] = vv.w * vv.y; X[5] = vv.w;
            X[6] = vv.x;        X[7] = vv.y;        X[8] = 1.0f;
            int idx = 0;
#pragma unroll
            for (int j = 0; j < 9; ++j) {
                float wXj = wt * X[j];
#pragma unroll
                for (int i = j; i < 9; ++i) {
                    acc[idx] += X[i] * wXj;
                    ++idx;
                }
            }
        }
#pragma unroll
        for (int k = 0; k < 45; ++k) {
            float vred = acc[k];
            for (int off = 32; off > 0; off >>= 1)
                vred += __shfl_down(vred, off, 64);
            acc[k] = vred;
        }
        if (lane == 0) {
#pragma unroll
            for (int k = 0; k < 45; ++k) red[v][k] = acc[k];
        }
    }
    __syncthreads();
    if (tid >= 64) return;

    // ========== wave 0 only: A fill, bit-identical to R4's sum ==========
    if (lane < 45) {
        double p0 = (double)red[0][lane]  + (double)red[1][lane]
                  + (double)red[2][lane]  + (double)red[3][lane];
        double p1 = (double)red[4][lane]  + (double)red[5][lane]
                  + (double)red[6][lane]  + (double)red[7][lane];
        double p2 = (double)red[8][lane]  + (double)red[9][lane]
                  + (double)red[10][lane] + (double)red[11][lane];
        double p3 = (double)red[12][lane] + (double)red[13][lane]
                  + (double)red[14][lane] + (double)red[15][lane];
        double s = ((p0 + p1) + p2) + p3;
        int idx = lane, j = 1;
        while (idx >= 10 - j) { idx -= (10 - j); ++j; }
        int i = j + idx;
        A[i][j] = (float)s;
    }

    // ---- ssytd2 ('L') : verbatim R4 ----
    for (int i = 1; i <= n - 1; ++i) {
        float alpha = A[i + 1][i];
        float ssq = 0.0f;
        for (int k = i + 2; k <= n; ++k) ssq += A[k][i] * A[k][i];
        float xnorm = sqrtf(ssq);
        float taui;
        if (xnorm == 0.0f) {
            taui = 0.0f;
            if (lane == 0) eel[i] = alpha;
        } else {
            float beta = -f_sign(slapy2(alpha, xnorm), alpha);
            taui = (beta - alpha) / beta;
            float sc = 1.0f / (alpha - beta);
            if (lane < 8 - i) {
                int k = i + 2 + lane;
                A[k][i] *= sc;
            }
            if (lane == 0) eel[i] = beta;
        }
        if (taui != 0.0f) {
            if (lane < 9 - i) {
                int r2 = i + 1 + lane;
                float s2 = 0.0f;
                for (int c2 = i + 1; c2 <= n; ++c2) {
                    float aval = (r2 >= c2) ? A[r2][c2] : A[c2][r2];
                    float vc = (c2 == i + 1) ? 1.0f : A[c2][i];
                    s2 += aval * vc;
                }
                wvl[r2] = taui * s2;
            }
            float dot = 0.0f;
            for (int k = i + 1; k <= n; ++k) {
                float vk = (k == i + 1) ? 1.0f : A[k][i];
                dot += wvl[k] * vk;
            }
            float alpha2 = -0.5f * taui * dot;
            if (lane < 9 - i) {
                int k = i + 1 + lane;
                float vk = (k == i + 1) ? 1.0f : A[k][i];
                wvl[k] += alpha2 * vk;
            }
            int kk = 9 - i;
            int cnt = kk * (kk + 1) / 2;
            if (lane < cnt) {
                int idx = lane, cc = 0;
                while (idx >= kk - cc) { idx -= (kk - cc); ++cc; }
                int c2 = i + 1 + cc;
                int r2 = c2 + idx;
                float vr = (r2 == i + 1) ? 1.0f : A[r2][i];
                float vc = (c2 == i + 1) ? 1.0f : A[c2][i];
                A[r2][c2] -= vr * wvl[c2] + wvl[r2] * vc;
            }
        }
        if (lane == 0) { ddl[i] = A[i][i]; tau[i] = taui; }
    }
    if (lane == 0) ddl[n] = A[n][n];

    // ---- handoff: LDS -> lane-distributed registers (verbatim R4) ----
    float r_dd, r_ee, r_cw, r_sw;
    float zz[10];
    r_dd = 0.0f; r_ee = 0.0f;
    if (lane >= 1 && lane <= 9) r_dd = ddl[lane];
    if (lane >= 1 && lane <= 8) r_ee = eel[lane];
#pragma unroll
    for (int c0 = 1; c0 <= 9; ++c0) zz[c0] = (lane == c0) ? 1.0f : 0.0f;

    // ---- ssteqr ('I') : verbatim R4 ----
    const float eps    = 5.9604645e-8f;
    const float eps2   = eps * eps;
    const float safmin = 1.17549435e-38f;
    const float safmax = 1.0f / 1.17549435e-38f;
    const float ssfmax = sqrtf(safmax) / 3.0f;
    const float ssfmin = sqrtf(safmin) / eps2;

    int nmaxit = n * 30, jtot = 0;
    int l1 = 1, nm1 = n - 1;
    int l, m, lsv, lend, lendsv, iscale;
    float anorm, p, g, r, c, s, f, btmp, rt1, rt2, tst, mul;

L10:
    if (l1 > n) goto L160;
    if (l1 > 1) r_ee = (lane == l1 - 1) ? 0.0f : r_ee;
    if (l1 <= nm1) {
        for (m = l1; m <= nm1; ++m) {
            tst = fabsf(rdl(r_ee, m));
            if (tst == 0.0f) goto L30;
            if (tst <= (sqrtf(fabsf(rdl(r_dd, m))) * sqrtf(fabsf(rdl(r_dd, m + 1)))) * eps) {
                r_ee = (lane == m) ? 0.0f : r_ee;
                goto L30;
            }
        }
    }
    m = n;
L30:
    l = l1; lsv = l; lend = m; lendsv = lend; l1 = m + 1;
    if (lend == l) goto L10;

    anorm = 0.0f;
    for (int k = l; k <= lend; ++k) anorm = fmaxf(anorm, fabsf(rdl(r_dd, k)));
    for (int k = l; k <= lend - 1; ++k) anorm = fmaxf(anorm, fabsf(rdl(r_ee, k)));
    iscale = 0;
    if (anorm == 0.0f) goto L10;
    if (anorm > ssfmax) {
        iscale = 1; mul = ssfmax / anorm;
        r_dd = (lane >= l && lane <= lend)     ? r_dd * mul : r_dd;
        r_ee = (lane >= l && lane <= lend - 1) ? r_ee * mul : r_ee;
    } else if (anorm < ssfmin) {
        iscale = 2; mul = ssfmin / anorm;
        r_dd = (lane >= l && lane <= lend)     ? r_dd * mul : r_dd;
        r_ee = (lane >= l && lane <= lend - 1) ? r_ee * mul : r_ee;
    }

    if (fabsf(rdl(r_dd, lend)) < fabsf(rdl(r_dd, l))) { lend = lsv; l = lendsv; }

    if (lend > l) {
        // ---------- QL ----------
L40:
        if (l != lend) {
            for (m = l; m <= lend - 1; ++m) {
                tst = fabsf(rdl(r_ee, m)); tst = tst * tst;
                if (tst <= (eps2 * fabsf(rdl(r_dd, m))) * fabsf(rdl(r_dd, m + 1)) + safmin) goto L60;
            }
        }
        m = lend;
L60:
        if (m < lend) r_ee = (lane == m) ? 0.0f : r_ee;
        p = rdl(r_dd, l);
        if (m == l) goto L80;
        if (m == l + 1) {
            slaev2(rdl(r_dd, l), rdl(r_ee, l), rdl(r_dd, l + 1), &rt1, &rt2, &c, &s);
            r_cw = 1.0f; r_sw = 0.0f;
            r_cw = (lane == l) ? c : r_cw;
            r_sw = (lane == l) ? s : r_sw;
            APPLY_QL();
            r_dd = (lane == l) ? rt1 : ((lane == l + 1) ? rt2 : r_dd);
            r_ee = (lane == l) ? 0.0f : r_ee;
            l += 2;
            if (l <= lend) goto L40;
            goto L140;
        }
        if (jtot == nmaxit) goto L140;
        ++jtot;
        g = (rdl(r_dd, l + 1) - p) / (2.0f * rdl(r_ee, l));
        r = slapy2(g, 1.0f);
        g = rdl(r_dd, m) - p + rdl(r_ee, l) / (g + f_sign(r, g));
        s = 1.0f; c = 1.0f; p = 0.0f;
        r_cw = 1.0f; r_sw = 0.0f;
        for (int i = m - 1; i >= l; --i) {
            float ei = rdl(r_ee, i);
            f = s * ei; btmp = c * ei;
            slartg(g, f, &c, &s, &r);
            if (i != m - 1) r_ee = (lane == i + 1) ? r : r_ee;
            g = rdl(r_dd, i + 1) - p;
            r = (rdl(r_dd, i) - g) * s + 2.0f * c * btmp;
            p = s * r;
            r_dd = (lane == i + 1) ? (g + p) : r_dd;
            g = c * r - btmp;
            r_cw = (lane == i) ? c : r_cw;
            r_sw = (lane == i) ? (-s) : r_sw;
        }
        APPLY_QL();
        r_dd = (lane == l) ? (r_dd - p) : r_dd;
        r_ee = (lane == l) ? g : r_ee;
        goto L40;
L80:
        r_dd = (lane == l) ? p : r_dd;
        l = l + 1;
        if (l <= lend) goto L40;
        goto L140;
    } else {
        // ---------- QR ----------
L90:
        if (l != lend) {
            for (m = l; m >= lend + 1; --m) {
                tst = fabsf(rdl(r_ee, m - 1)); tst = tst * tst;
                if (tst <= (eps2 * fabsf(rdl(r_dd, m))) * fabsf(rdl(r_dd, m - 1)) + safmin) goto L110;
            }
        }
        m = lend;
L110:
        if (m > lend) r_ee = (lane == m - 1) ? 0.0f : r_ee;
        p = rdl(r_dd, l);
        if (m == l) goto L130;
        if (m == l - 1) {
            slaev2(rdl(r_dd, l - 1), rdl(r_ee, l - 1), rdl(r_dd, l), &rt1, &rt2, &c, &s);
            r_cw = 1.0f; r_sw = 0.0f;
            r_cw = (lane == l - 1) ? c : r_cw;
            r_sw = (lane == l - 1) ? s : r_sw;
            APPLY_QR();
            r_dd = (lane == l - 1) ? rt1 : ((lane == l) ? rt2 : r_dd);
            r_ee = (lane == l - 1) ? 0.0f : r_ee;
            l -= 2;
            if (l >= lend) goto L90;
            goto L140;
        }
        if (jtot == nmaxit) goto L140;
        ++jtot;
        g = (rdl(r_dd, l - 1) - p) / (2.0f * rdl(r_ee, l - 1));
        r = slapy2(g, 1.0f);
        g = rdl(r_dd, m) - p + rdl(r_ee, l - 1) / (g + f_sign(r, g));
        s = 1.0f; c = 1.0f; p = 0.0f;
        r_cw = 1.0f; r_sw = 0.0f;
        for (int i = m; i <= l - 1; ++i) {
            float ei = rdl(r_ee, i);
            f = s * ei; btmp = c * ei;
            slartg(g, f, &c, &s, &r);
            if (i != m) r_ee = (lane == i - 1) ? r : r_ee;
            g = rdl(r_dd, i) - p;
            r = (rdl(r_dd, i + 1) - g) * s + 2.0f * c * btmp;
            p = s * r;
            r_dd = (lane == i) ? (g + p) : r_dd;
            g = c * r - btmp;
            r_cw = (lane == i) ? c : r_cw;
            r_sw = (lane == i) ? s : r_sw;
        }
        APPLY_QR();
        r_dd = (lane == l) ? (r_dd - p) : r_dd;
        r_ee = (lane == l - 1) ? g : r_ee;
        goto L90;
L130:
        r_dd = (lane == l) ? p : r_dd;
        l = l - 1;
        if (l >= lend) goto L90;
        goto L140;
    }

L140:
    if (iscale == 1) {
        mul = anorm / ssfmax;
        r_dd = (lane >= lsv && lane <= lendsv)     ? r_dd * mul : r_dd;
        r_ee = (lane >= lsv && lane <= lendsv - 1) ? r_ee * mul : r_ee;
    } else if (iscale == 2) {
        mul = anorm / ssfmin;
        r_dd = (lane >= lsv && lane <= lendsv)     ? r_dd * mul : r_dd;
        r_ee = (lane >= lsv && lane <= lendsv - 1) ? r_ee * mul : r_ee;
    }
    if (jtot < nmaxit) goto L10;
    goto L160;

L160:
    // dump Z registers to LDS for the dynamic-index sort + epilogue
    if (lane >= 1 && lane <= 9) {
#pragma unroll
        for (int c0 = 1; c0 <= 9; ++c0) Zl[lane][c0] = zz[c0];
    }

    // selection sort ascending (strict '<', matches ssteqr)
    for (int ii = 2; ii <= n; ++ii) {
        int i = ii - 1, k = i;
        p = rdl(r_dd, i);
        for (int j = ii; j <= n; ++j) {
            float dj = rdl(r_dd, j);
            if (dj < p) { k = j; p = dj; }
        }
        if (k != i) {
            float di = rdl(r_dd, i);
            r_dd = (lane == k) ? di : r_dd;
            r_dd = (lane == i) ? p  : r_dd;
            if (lane >= 1 && lane <= 9) {
                float t = Zl[lane][i]; Zl[lane][i] = Zl[lane][k]; Zl[lane][k] = t;
            }
        }
    }

    // ---- apply Q (sormtr 'L','L','N') to Z(:,1), then normalize ----
    if (lane < 9) zvl[lane + 1] = Zl[lane + 1][1];
    for (int i2 = n - 1; i2 >= 1; --i2) {
        float ti = tau[i2];
        if (ti != 0.0f) {
            float dotp = zvl[i2 + 1];
            for (int k = i2 + 2; k <= n; ++k) dotp += A[k][i2] * zvl[k];
            float t = ti * dotp;
            if (lane < 9 - i2) {
                int k = i2 + 1 + lane;
                float upd = (k == i2 + 1) ? t : t * A[k][i2];
                zvl[k] -= upd;
            }
        }
    }
    {
        float nrm = 0.0f;
        for (int row = 1; row <= n; ++row) nrm += zvl[row] * zvl[row];
        nrm = sqrtf(nrm);
        if (lane < 9) out[(size_t)b * 9 + lane] = zvl[lane + 1] / nrm;
    }
}

extern "C" void kernel_launch(void* const* d_in, const int* in_sizes, int n_in,
                              void* d_out, int out_size, void* d_ws, size_t ws_size,
                              hipStream_t stream) {
    const float4* x = (const float4*)d_in[0];   // (256,1,20000,4) f32
    const float*  w = (const float*)d_in[1];    // (256,20000) f32
    float* out = (float*)d_out;                 // (256,9) f32
    (void)d_ws; (void)ws_size;

    fused_kernel<<<dim3(BATCH), dim3(512), 0, stream>>>(x, w, out);
}

// Round 7
// 182.432 us; speedup vs baseline: 1.0607x; 1.0607x over previous
//
#include <hip/hip_runtime.h>
#include <math.h>

#define BATCH 256
#define NPTS  20000

// =====================================================================
// R7 = R6 with (1) gram at 1024 threads/block: 16 real waves = R6's 16
// virtual waves, bit-identical partials & double-sum; (2) ssteqr serial
// convergence scans / anorm replaced by ballot / shuffle-tree equivalents
// (provably same m selection, exact fmax). Sweep recurrence verbatim R6.
// =====================================================================

__device__ __forceinline__ float f_sign(float a, float b) {
    return (b >= 0.0f) ? fabsf(a) : -fabsf(a);
}

__device__ __forceinline__ float slapy2(float xx, float yy) {
    float xa = fabsf(xx), ya = fabsf(yy);
    float w_ = fmaxf(xa, ya), z_ = fminf(xa, ya);
    if (z_ == 0.0f) return w_;
    float t = z_ / w_;
    return w_ * sqrtf(1.0f + t * t);
}

__device__ __forceinline__ float rdl(float v, int i) {
    return __int_as_float(__builtin_amdgcn_readlane(__float_as_int(v), i));
}

__device__ __forceinline__ float rfl(float v) {
    return __int_as_float(__builtin_amdgcn_readfirstlane(__float_as_int(v)));
}

// bits lo..hi inclusive (0 <= lo, hi <= 62), 0 if empty
__device__ __forceinline__ unsigned long long lanerange(int lo, int hi) {
    if (hi < lo) return 0ull;
    return (1ull << (hi + 1)) - (1ull << lo);
}

// LAPACK 3.10+ slartg; ssteqr passes (G, F) -- G first.
__device__ __forceinline__ void slartg(float f, float g, float* cs, float* sn, float* r) {
    if (g == 0.0f) { *cs = 1.0f; *sn = 0.0f; *r = f; }
    else if (f == 0.0f) { *cs = 0.0f; *sn = (g >= 0.0f) ? 1.0f : -1.0f; *r = fabsf(g); }
    else {
        float dd2 = sqrtf(f * f + g * g);
        *cs = fabsf(f) / dd2;
        *r  = f_sign(dd2, f);
        *sn = g / (*r);
    }
}

__device__ void slaev2(float a, float b, float c_, float* rt1, float* rt2,
                       float* cs1, float* sn1) {
    float sm = a + c_;
    float df = a - c_;
    float adf = fabsf(df);
    float tb = b + b;
    float ab = fabsf(tb);
    float acmx, acmn;
    if (fabsf(a) > fabsf(c_)) { acmx = a; acmn = c_; } else { acmx = c_; acmn = a; }
    float rt;
    if (adf > ab)      { float t = ab / adf; rt = adf * sqrtf(1.0f + t * t); }
    else if (adf < ab) { float t = adf / ab; rt = ab * sqrtf(1.0f + t * t); }
    else               { rt = ab * sqrtf(2.0f); }
    int sgn1;
    if (sm < 0.0f) {
        *rt1 = 0.5f * (sm - rt); sgn1 = -1;
        *rt2 = (acmx / (*rt1)) * acmn - (b / (*rt1)) * b;
    } else if (sm > 0.0f) {
        *rt1 = 0.5f * (sm + rt); sgn1 = 1;
        *rt2 = (acmx / (*rt1)) * acmn - (b / (*rt1)) * b;
    } else {
        *rt1 = 0.5f * rt; *rt2 = -0.5f * rt; sgn1 = 1;
    }
    float cs; int sgn2;
    if (df >= 0.0f) { cs = df + rt; sgn2 = 1; } else { cs = df - rt; sgn2 = -1; }
    float acs = fabsf(cs);
    if (acs > ab) {
        float ct = -tb / cs;
        *sn1 = 1.0f / sqrtf(1.0f + ct * ct);
        *cs1 = ct * (*sn1);
    } else {
        if (ab == 0.0f) { *cs1 = 1.0f; *sn1 = 0.0f; }
        else {
            float tn = -cs / tb;
            *cs1 = 1.0f / sqrtf(1.0f + tn * tn);
            *sn1 = tn * (*cs1);
        }
    }
    if (sgn1 == sgn2) { float tn = *cs1; *cs1 = -(*sn1); *sn1 = tn; }
}

#define APPLY_QL() do { \
    _Pragma("unroll") \
    for (int jz = 8; jz >= 1; --jz) { \
        float cj = rdl(r_cw, jz), sj = rdl(r_sw, jz); \
        float tmpz = zz[jz + 1]; \
        zz[jz + 1] = cj * tmpz - sj * zz[jz]; \
        zz[jz]     = sj * tmpz + cj * zz[jz]; \
    } } while (0)

#define APPLY_QR() do { \
    _Pragma("unroll") \
    for (int jz = 1; jz <= 8; ++jz) { \
        float cj = rdl(r_cw, jz), sj = rdl(r_sw, jz); \
        float tmpz = zz[jz + 1]; \
        zz[jz + 1] = cj * tmpz - sj * zz[jz]; \
        zz[jz]     = sj * tmpz + cj * zz[jz]; \
    } } while (0)

__global__ __launch_bounds__(1024) void fused_kernel(
    const float4* __restrict__ x, const float* __restrict__ wgt,
    float* __restrict__ out)
{
    const int n = 9;
    int b = blockIdx.x;
    int tid = threadIdx.x;
    int lane = tid & 63;
    int rw = tid >> 6;             // real wave 0..15 == virtual wave

    __shared__ float red[16][45];
    __shared__ float A[10][10];
    __shared__ float Zl[10][10];
    __shared__ float ddl[11], eel[11], tau[10], wvl[10], zvl[10];

    // ========== gram phase: 16 waves, one virtual wave each ==========
    // Same per-lane point sequences & butterfly as R6 -> bit-identical.
    {
        int chunk = rw >> 2, wvc = rw & 3;
        float acc[45];
#pragma unroll
        for (int k = 0; k < 45; ++k) acc[k] = 0.0f;

        const float4* xb = x + (size_t)b * NPTS;
        const float*  wb = wgt + (size_t)b * NPTS;
        int base = chunk * 5000;
        for (int nn = base + wvc * 64 + lane; nn < base + 5000; nn += 256) {
            float4 vv = xb[nn];
            float wt = wb[nn];
            float X[9];
            X[0] = vv.z * vv.x; X[1] = vv.z * vv.y; X[2] = vv.z;
            X[3] = vv.w * vv.x; X[4] = vv.w * vv.y; X[5] = vv.w;
            X[6] = vv.x;        X[7] = vv.y;        X[8] = 1.0f;
            int idx = 0;
#pragma unroll
            for (int j = 0; j < 9; ++j) {
                float wXj = wt * X[j];
#pragma unroll
                for (int i = j; i < 9; ++i) {
                    acc[idx] += X[i] * wXj;
                    ++idx;
                }
            }
        }
#pragma unroll
        for (int k = 0; k < 45; ++k) {
            float vred = acc[k];
            for (int off = 32; off > 0; off >>= 1)
                vred += __shfl_down(vred, off, 64);
            acc[k] = vred;
        }
        if (lane == 0) {
#pragma unroll
            for (int k = 0; k < 45; ++k) red[rw][k] = acc[k];
        }
    }
    __syncthreads();
    if (tid >= 64) return;

    // ========== wave 0 only: A fill, bit-identical to R4/R6 sum ==========
    if (lane < 45) {
        double p0 = (double)red[0][lane]  + (double)red[1][lane]
                  + (double)red[2][lane]  + (double)red[3][lane];
        double p1 = (double)red[4][lane]  + (double)red[5][lane]
                  + (double)red[6][lane]  + (double)red[7][lane];
        double p2 = (double)red[8][lane]  + (double)red[9][lane]
                  + (double)red[10][lane] + (double)red[11][lane];
        double p3 = (double)red[12][lane] + (double)red[13][lane]
                  + (double)red[14][lane] + (double)red[15][lane];
        double s = ((p0 + p1) + p2) + p3;
        int idx = lane, j = 1;
        while (idx >= 10 - j) { idx -= (10 - j); ++j; }
        int i = j + idx;
        A[i][j] = (float)s;
    }

    // ---- ssytd2 ('L') : verbatim ----
    for (int i = 1; i <= n - 1; ++i) {
        float alpha = A[i + 1][i];
        float ssq = 0.0f;
        for (int k = i + 2; k <= n; ++k) ssq += A[k][i] * A[k][i];
        float xnorm = sqrtf(ssq);
        float taui;
        if (xnorm == 0.0f) {
            taui = 0.0f;
            if (lane == 0) eel[i] = alpha;
        } else {
            float beta = -f_sign(slapy2(alpha, xnorm), alpha);
            taui = (beta - alpha) / beta;
            float sc = 1.0f / (alpha - beta);
            if (lane < 8 - i) {
                int k = i + 2 + lane;
                A[k][i] *= sc;
            }
            if (lane == 0) eel[i] = beta;
        }
        if (taui != 0.0f) {
            if (lane < 9 - i) {
                int r2 = i + 1 + lane;
                float s2 = 0.0f;
                for (int c2 = i + 1; c2 <= n; ++c2) {
                    float aval = (r2 >= c2) ? A[r2][c2] : A[c2][r2];
                    float vc = (c2 == i + 1) ? 1.0f : A[c2][i];
                    s2 += aval * vc;
                }
                wvl[r2] = taui * s2;
            }
            float dot = 0.0f;
            for (int k = i + 1; k <= n; ++k) {
                float vk = (k == i + 1) ? 1.0f : A[k][i];
                dot += wvl[k] * vk;
            }
            float alpha2 = -0.5f * taui * dot;
            if (lane < 9 - i) {
                int k = i + 1 + lane;
                float vk = (k == i + 1) ? 1.0f : A[k][i];
                wvl[k] += alpha2 * vk;
            }
            int kk = 9 - i;
            int cnt = kk * (kk + 1) / 2;
            if (lane < cnt) {
                int idx = lane, cc = 0;
                while (idx >= kk - cc) { idx -= (kk - cc); ++cc; }
                int c2 = i + 1 + cc;
                int r2 = c2 + idx;
                float vr = (r2 == i + 1) ? 1.0f : A[r2][i];
                float vc = (c2 == i + 1) ? 1.0f : A[c2][i];
                A[r2][c2] -= vr * wvl[c2] + wvl[r2] * vc;
            }
        }
        if (lane == 0) { ddl[i] = A[i][i]; tau[i] = taui; }
    }
    if (lane == 0) ddl[n] = A[n][n];

    // ---- handoff: lane-distributed registers ----
    float r_dd, r_ee, r_cw, r_sw;
    float zz[10];
    r_dd = 0.0f; r_ee = 0.0f;
    if (lane >= 1 && lane <= 9) r_dd = ddl[lane];
    if (lane >= 1 && lane <= 8) r_ee = eel[lane];
#pragma unroll
    for (int c0 = 1; c0 <= 9; ++c0) zz[c0] = (lane == c0) ? 1.0f : 0.0f;

    // ---- ssteqr ('I') with ballot scans ----
    const float eps    = 5.9604645e-8f;
    const float eps2   = eps * eps;
    const float safmin = 1.17549435e-38f;
    const float safmax = 1.0f / 1.17549435e-38f;
    const float ssfmax = sqrtf(safmax) / 3.0f;
    const float ssfmin = sqrtf(safmin) / eps2;

    int nmaxit = n * 30, jtot = 0;
    int l1 = 1, nm1 = n - 1;
    int l, m, lsv, lend, lendsv, iscale;
    float anorm, p, g, r, c, s, f, btmp, rt1, rt2, mul;

L10:
    if (l1 > n) goto L160;
    if (l1 > 1) r_ee = (lane == l1 - 1) ? 0.0f : r_ee;
    if (l1 <= nm1) {
        // parallel scan: first m in [l1, nm1] with |e[m]| <= sqrt|d[m]|*sqrt|d[m+1]|*eps
        // (the serial tst==0 break is subsumed: thr >= 0)
        float dmp1 = __shfl_down(r_dd, 1, 64);
        bool pred = (fabsf(r_ee) <= (sqrtf(fabsf(r_dd)) * sqrtf(fabsf(dmp1))) * eps);
        unsigned long long msk = __ballot(pred) & lanerange(l1, nm1);
        if (msk) {
            m = (int)__builtin_ctzll(msk);
            r_ee = (lane == m) ? 0.0f : r_ee;   // no-op (or -0 -> +0) when tst==0
        } else m = n;
    } else m = n;

    l = l1; lsv = l; lend = m; lendsv = lend; l1 = m + 1;
    if (lend == l) goto L10;

    // anorm: exact shuffle-max tree (fmax associative & commutative)
    {
        float av = 0.0f;
        if (lane >= l && lane <= lend)     av = fabsf(r_dd);
        if (lane >= l && lane <= lend - 1) av = fmaxf(av, fabsf(r_ee));
        for (int off = 32; off > 0; off >>= 1)
            av = fmaxf(av, __shfl_down(av, off, 64));
        anorm = rfl(av);
    }
    iscale = 0;
    if (anorm == 0.0f) goto L10;
    if (anorm > ssfmax) {
        iscale = 1; mul = ssfmax / anorm;
        r_dd = (lane >= l && lane <= lend)     ? r_dd * mul : r_dd;
        r_ee = (lane >= l && lane <= lend - 1) ? r_ee * mul : r_ee;
    } else if (anorm < ssfmin) {
        iscale = 2; mul = ssfmin / anorm;
        r_dd = (lane >= l && lane <= lend)     ? r_dd * mul : r_dd;
        r_ee = (lane >= l && lane <= lend - 1) ? r_ee * mul : r_ee;
    }

    if (fabsf(rdl(r_dd, lend)) < fabsf(rdl(r_dd, l))) { lend = lsv; l = lendsv; }

    if (lend > l) {
        // ---------- QL ----------
L40:
        {
            // first m in [l, lend-1] with |e[m]|^2 <= (eps2*|d[m]|)*|d[m+1]| + safmin
            float dmp1 = __shfl_down(r_dd, 1, 64);
            float t2 = fabsf(r_ee); t2 = t2 * t2;
            bool pred = (t2 <= (eps2 * fabsf(r_dd)) * fabsf(dmp1) + safmin);
            unsigned long long msk = __ballot(pred) & lanerange(l, lend - 1);
            if (msk) {
                m = (int)__builtin_ctzll(msk);
                r_ee = (lane == m) ? 0.0f : r_ee;   // serial: if m<lend -> e[m]=0
            } else m = lend;
        }
        p = rdl(r_dd, l);
        if (m == l) goto L80;
        if (m == l + 1) {
            slaev2(rdl(r_dd, l), rdl(r_ee, l), rdl(r_dd, l + 1), &rt1, &rt2, &c, &s);
            r_cw = 1.0f; r_sw = 0.0f;
            r_cw = (lane == l) ? c : r_cw;
            r_sw = (lane == l) ? s : r_sw;
            APPLY_QL();
            r_dd = (lane == l) ? rt1 : ((lane == l + 1) ? rt2 : r_dd);
            r_ee = (lane == l) ? 0.0f : r_ee;
            l += 2;
            if (l <= lend) goto L40;
            goto L140;
        }
        if (jtot == nmaxit) goto L140;
        ++jtot;
        g = (rdl(r_dd, l + 1) - p) / (2.0f * rdl(r_ee, l));
        r = slapy2(g, 1.0f);
        g = rdl(r_dd, m) - p + rdl(r_ee, l) / (g + f_sign(r, g));
        s = 1.0f; c = 1.0f; p = 0.0f;
        r_cw = 1.0f; r_sw = 0.0f;
        for (int i = m - 1; i >= l; --i) {
            float ei = rdl(r_ee, i);
            f = s * ei; btmp = c * ei;
            slartg(g, f, &c, &s, &r);
            if (i != m - 1) r_ee = (lane == i + 1) ? r : r_ee;
            g = rdl(r_dd, i + 1) - p;
            r = (rdl(r_dd, i) - g) * s + 2.0f * c * btmp;
            p = s * r;
            r_dd = (lane == i + 1) ? (g + p) : r_dd;
            g = c * r - btmp;
            r_cw = (lane == i) ? c : r_cw;
            r_sw = (lane == i) ? (-s) : r_sw;
        }
        APPLY_QL();
        r_dd = (lane == l) ? (r_dd - p) : r_dd;
        r_ee = (lane == l) ? g : r_ee;
        goto L40;
L80:
        r_dd = (lane == l) ? p : r_dd;
        l = l + 1;
        if (l <= lend) goto L40;
        goto L140;
    } else {
        // ---------- QR ----------
L90:
        {
            // descending m=l..lend+1: pred on e[m-1],d[m],d[m-1]; lane j=m-1
            float djp1 = __shfl_down(r_dd, 1, 64);   // d[j+1] = d[m]
            float t2 = fabsf(r_ee); t2 = t2 * t2;    // |e[j]|^2
            bool pred = (t2 <= (eps2 * fabsf(djp1)) * fabsf(r_dd) + safmin);
            unsigned long long msk = __ballot(pred) & lanerange(lend, l - 1);
            if (msk) {
                int j = 63 - (int)__builtin_clzll(msk);  // largest j -> first descending m
                m = j + 1;
                r_ee = (lane == j) ? 0.0f : r_ee;        // serial: if m>lend -> e[m-1]=0
            } else m = lend;
        }
        p = rdl(r_dd, l);
        if (m == l) goto L130;
        if (m == l - 1) {
            slaev2(rdl(r_dd, l - 1), rdl(r_ee, l - 1), rdl(r_dd, l), &rt1, &rt2, &c, &s);
            r_cw = 1.0f; r_sw = 0.0f;
            r_cw = (lane == l - 1) ? c : r_cw;
            r_sw = (lane == l - 1) ? s : r_sw;
            APPLY_QR();
            r_dd = (lane == l - 1) ? rt1 : ((lane == l) ? rt2 : r_dd);
            r_ee = (lane == l - 1) ? 0.0f : r_ee;
            l -= 2;
            if (l >= lend) goto L90;
            goto L140;
        }
        if (jtot == nmaxit) goto L140;
        ++jtot;
        g = (rdl(r_dd, l - 1) - p) / (2.0f * rdl(r_ee, l - 1));
        r = slapy2(g, 1.0f);
        g = rdl(r_dd, m) - p + rdl(r_ee, l - 1) / (g + f_sign(r, g));
        s = 1.0f; c = 1.0f; p = 0.0f;
        r_cw = 1.0f; r_sw = 0.0f;
        for (int i = m; i <= l - 1; ++i) {
            float ei = rdl(r_ee, i);
            f = s * ei; btmp = c * ei;
            slartg(g, f, &c, &s, &r);
            if (i != m) r_ee = (lane == i - 1) ? r : r_ee;
            g = rdl(r_dd, i) - p;
            r = (rdl(r_dd, i + 1) - g) * s + 2.0f * c * btmp;
            p = s * r;
            r_dd = (lane == i) ? (g + p) : r_dd;
            g = c * r - btmp;
            r_cw = (lane == i) ? c : r_cw;
            r_sw = (lane == i) ? s : r_sw;
        }
        APPLY_QR();
        r_dd = (lane == l) ? (r_dd - p) : r_dd;
        r_ee = (lane == l - 1) ? g : r_ee;
        goto L90;
L130:
        r_dd = (lane == l) ? p : r_dd;
        l = l - 1;
        if (l >= lend) goto L90;
        goto L140;
    }

L140:
    if (iscale == 1) {
        mul = anorm / ssfmax;
        r_dd = (lane >= lsv && lane <= lendsv)     ? r_dd * mul : r_dd;
        r_ee = (lane >= lsv && lane <= lendsv - 1) ? r_ee * mul : r_ee;
    } else if (iscale == 2) {
        mul = anorm / ssfmin;
        r_dd = (lane >= lsv && lane <= lendsv)     ? r_dd * mul : r_dd;
        r_ee = (lane >= lsv && lane <= lendsv - 1) ? r_ee * mul : r_ee;
    }
    if (jtot < nmaxit) goto L10;
    goto L160;

L160:
    if (lane >= 1 && lane <= 9) {
#pragma unroll
        for (int c0 = 1; c0 <= 9; ++c0) Zl[lane][c0] = zz[c0];
    }

    // selection sort ascending (strict '<', matches ssteqr)
    for (int ii = 2; ii <= n; ++ii) {
        int i = ii - 1, k = i;
        p = rdl(r_dd, i);
        for (int j = ii; j <= n; ++j) {
            float dj = rdl(r_dd, j);
            if (dj < p) { k = j; p = dj; }
        }
        if (k != i) {
            float di = rdl(r_dd, i);
            r_dd = (lane == k) ? di : r_dd;
            r_dd = (lane == i) ? p  : r_dd;
            if (lane >= 1 && lane <= 9) {
                float t = Zl[lane][i]; Zl[lane][i] = Zl[lane][k]; Zl[lane][k] = t;
            }
        }
    }

    // ---- apply Q (sormtr 'L','L','N') to Z(:,1), then normalize ----
    if (lane < 9) zvl[lane + 1] = Zl[lane + 1][1];
    for (int i2 = n - 1; i2 >= 1; --i2) {
        float ti = tau[i2];
        if (ti != 0.0f) {
            float dotp = zvl[i2 + 1];
            for (int k = i2 + 2; k <= n; ++k) dotp += A[k][i2] * zvl[k];
            float t = ti * dotp;
            if (lane < 9 - i2) {
                int k = i2 + 1 + lane;
                float upd = (k == i2 + 1) ? t : t * A[k][i2];
                zvl[k] -= upd;
            }
        }
    }
    {
        float nrm = 0.0f;
        for (int row = 1; row <= n; ++row) nrm += zvl[row] * zvl[row];
        nrm = sqrtf(nrm);
        if (lane < 9) out[(size_t)b * 9 + lane] = zvl[lane + 1] / nrm;
    }
}

extern "C" void kernel_launch(void* const* d_in, const int* in_sizes, int n_in,
                              void* d_out, int out_size, void* d_ws, size_t ws_size,
                              hipStream_t stream) {
    const float4* x = (const float4*)d_in[0];   // (256,1,20000,4) f32
    const float*  w = (const float*)d_in[1];    // (256,20000) f32
    float* out = (float*)d_out;                 // (256,9) f32
    (void)d_ws; (void)ws_size;

    fused_kernel<<<dim3(BATCH), dim3(1024), 0, stream>>>(x, w, out);
}